// Round 12
// baseline (95.707 us; speedup 1.0000x reference)
//
#include <hip/hip_runtime.h>
#include <hip/hip_bf16.h>
#include <math.h>
#include <stdint.h>

#define DM 4096
#define NEXP 64
#define BK 64              // k per chunk
#define NCH (DM / BK)      // 64 chunks
#define TOKW 16            // tokens per block (one 16-row MFMA tile)
#define KSPLIT 8           // waves per block, each owns NCH/KSPLIT chunks
#define CHPS (NCH / KSPLIT)

typedef short bf16x8 __attribute__((ext_vector_type(8)));
typedef float f32x4  __attribute__((ext_vector_type(4)));

// RN split: x = hi + lo + f, |f| <= 2^-18 |x|. lo = x - hi is Sterbenz-exact.
__device__ __forceinline__ void split2(float f0, float f1, uint32_t& hw, uint32_t& lw) {
    float2 ff; ff.x = f0; ff.y = f1;
    __hip_bfloat162 h = __float22bfloat162_rn(ff);
    union { __hip_bfloat162 b; uint32_t u; } ch; ch.b = h;
    hw = ch.u;
    float h0 = __bfloat162float(h.x);
    float h1 = __bfloat162float(h.y);
    float2 gg; gg.x = f0 - h0; gg.y = f1 - h1;
    __hip_bfloat162 l = __float22bfloat162_rn(gg);
    union { __hip_bfloat162 b; uint32_t u; } cl; cl.b = l;
    lw = cl.u;
}

// ---------------- pre-pass: W fp32 -> RN bf16 hi/lo, fragment-ordered blob ----------------
// blob byte layout: c*16384 + ks*4096 + n4*1024 + lane*16 (hi; +8192 for lo)
// where lane = (e&15) | ((kgran&3)<<4), n4 = e>>4, ks = kgran>>2.
// 256 blocks (64 chunks x 4 expert-quarters) so the pre-pass spreads across CUs.
__global__ __launch_bounds__(128) void wsplit_kernel(const float* __restrict__ W,
                                                     char* __restrict__ blob) {
    const int c   = blockIdx.x;        // 0..63
    const int eq  = blockIdx.y;        // 0..3
    const int tid = threadIdx.x;       // 0..127
    const int e   = eq * 16 + (tid >> 3);  // expert 0..63
    const int g   = tid & 7;           // k-granule 0..7 (8 bf16 each)

    const float* src = W + (size_t)e * DM + c * BK + g * 8;
    float x[8];
    *(float4*)(x)     = *(const float4*)(src);
    *(float4*)(x + 4) = *(const float4*)(src + 4);

    uint32_t hiw[4], low[4];
#pragma unroll
    for (int j = 0; j < 4; ++j) split2(x[2 * j], x[2 * j + 1], hiw[j], low[j]);

    const int ks = g >> 2;
    const int ln = (e & 15) | ((g & 3) << 4);
    const int n4 = e >> 4;
    const size_t base = (size_t)c * 16384 + (size_t)ks * 4096 + (size_t)n4 * 1024 + (size_t)ln * 16;
    *(uint4*)(blob + base)        = *(uint4*)hiw;   // hi plane
    *(uint4*)(blob + base + 8192) = *(uint4*)low;   // lo plane
}

// ---------------- main kernel ----------------
// 512 threads = 8 waves, no barriers in the K-loop. All waves share the
// block's 16 tokens; wave w owns K-chunks [w*CHPS,(w+1)*CHPS). m=1 tile
// per wave keeps VGPR ~<=85 so launch_bounds(512,6) gives 24 waves/CU.
// 3-product split GEMM: hh + hl + lh (ll term ~3e-6 logit error, dropped).
__global__ __launch_bounds__(512, 6) void router_mfma_kernel(
    const float* __restrict__ X,
    const char* __restrict__ blob,
    const float* __restrict__ Bv,
    float* __restrict__ out)
{
    __shared__ float part[KSPLIT][TOKW][66];   // 33 KiB, padded stride

    const int tid  = threadIdx.x;      // 0..511
    const int lane = tid & 63;
    const int wv   = tid >> 6;         // 0..7 = K-slice
    const long tok0 = (long)blockIdx.x * TOKW;

    const int tk = lane & 15;          // token row / expert col
    const int kg = lane >> 4;          // k-granule within 32-k subtile

    // per-lane A row base (floats), at this wave's K-slice origin
    const float* a0 = X + (size_t)(tok0 + tk) * DM + (size_t)wv * (CHPS * BK) + kg * 8;
    const char*  bw = blob + (size_t)(wv * CHPS) * 16384;

    f32x4 acc[4];
#pragma unroll
    for (int n = 0; n < 4; ++n) acc[n] = (f32x4)0.0f;

#pragma unroll 1
    for (int ci = 0; ci < CHPS; ++ci) {
        const char* bb = bw + (size_t)ci * 16384;

        // ---- A: 8 floats per ks, per-lane direct from global ----
        float ar[2][8];   // [ks][8]
#pragma unroll
        for (int ks = 0; ks < 2; ++ks) {
            const float* p = a0 + ci * BK + ks * 32;
            *(float4*)(ar[ks])     = *(const float4*)(p);
            *(float4*)(ar[ks] + 4) = *(const float4*)(p + 4);
        }

        // split to fragments
        bf16x8 ah[2], al[2];   // [ks]
#pragma unroll
        for (int ks = 0; ks < 2; ++ks) {
            uint32_t hw[4], lw[4];
#pragma unroll
            for (int j = 0; j < 4; ++j)
                split2(ar[ks][2 * j], ar[ks][2 * j + 1], hw[j], lw[j]);
            ah[ks] = *(bf16x8*)hw;
            al[ks] = *(bf16x8*)lw;
        }

        // ---- B from L2 (fragment-ordered blob) + MFMA (3 products) ----
#pragma unroll
        for (int ks = 0; ks < 2; ++ks) {
#pragma unroll
            for (int n = 0; n < 4; ++n) {
                const size_t bo = (size_t)ks * 4096 + (size_t)n * 1024 + (size_t)lane * 16;
                bf16x8 bh = *(const bf16x8*)(bb + bo);
                bf16x8 bl = *(const bf16x8*)(bb + 8192 + bo);
                acc[n] = __builtin_amdgcn_mfma_f32_16x16x32_bf16(ah[ks], bh, acc[n], 0, 0, 0);
                acc[n] = __builtin_amdgcn_mfma_f32_16x16x32_bf16(ah[ks], bl, acc[n], 0, 0, 0);
                acc[n] = __builtin_amdgcn_mfma_f32_16x16x32_bf16(al[ks], bh, acc[n], 0, 0, 0);
            }
        }
    }

    // ---- write per-slice partial logits: token = kg*4 + r, expert = n*16 + tk ----
#pragma unroll
    for (int n = 0; n < 4; ++n)
#pragma unroll
        for (int r = 0; r < 4; ++r)
            part[wv][kg * 4 + r][n * 16 + tk] = acc[n][r];
    __syncthreads();

    // ---- reduce over K-slices: 1024 cells, 2 per thread ----
#pragma unroll
    for (int i = 0; i < 2; ++i) {
        const int cell = tid + i * 512;
        const int t = cell >> 6;
        const int e = cell & 63;
        float s = part[0][t][e];
#pragma unroll
        for (int w = 1; w < KSPLIT; ++w) s += part[w][t][e];
        part[0][t][e] = s;
    }
    __syncthreads();

    // ---- epilogue: bias + softmax + top-2 + dense scatter (lane = expert) ----
    const float bias = Bv[lane];
#pragma unroll 1
    for (int j = 0; j < TOKW / KSPLIT; ++j) {
        const int t = wv * (TOKW / KSPLIT) + j;
        float v = part[0][t][lane] + bias;

        float m1 = v;        int i1 = lane;
        float m2 = -3.4e38f; int i2 = 127;
#pragma unroll
        for (int s = 1; s < 64; s <<= 1) {
            float om1 = __shfl_xor(m1, s, 64);
            int   oi1 = __shfl_xor(i1, s, 64);
            float om2 = __shfl_xor(m2, s, 64);
            int   oi2 = __shfl_xor(i2, s, 64);
            bool bw2 = (om1 > m1) || (om1 == m1 && oi1 < i1);
            float l1v = bw2 ? m1 : om1;  int l1i = bw2 ? i1 : oi1;
            float w2v = bw2 ? om2 : m2;  int w2i = bw2 ? oi2 : i2;
            if (bw2) { m1 = om1; i1 = oi1; }
            bool tw = (l1v > w2v) || (l1v == w2v && l1i < w2i);
            m2 = tw ? l1v : w2v;  i2 = tw ? l1i : w2i;
        }

        float p = expf(v - m1);
        float ssum = p;
#pragma unroll
        for (int s = 1; s < 64; s <<= 1) ssum += __shfl_xor(ssum, s, 64);

        float sc = (lane == i1 || lane == i2) ? (p / ssum) : 0.0f;
        out[(size_t)(tok0 + t) * NEXP + lane] = sc;
    }
}

extern "C" void kernel_launch(void* const* d_in, const int* in_sizes, int n_in,
                              void* d_out, int out_size, void* d_ws, size_t ws_size,
                              hipStream_t stream) {
    const float* X  = (const float*)d_in[0];   // [4,4096,4096] fp32
    const float* W  = (const float*)d_in[1];   // [64,4096] fp32
    const float* Bv = (const float*)d_in[2];   // [64] fp32
    float* out = (float*)d_out;                // [4,4096,64] fp32

    // W split blob: 64 chunks * 16 KiB = 1 MiB in d_ws
    char* blob = (char*)d_ws;
    wsplit_kernel<<<dim3(NCH, 4), dim3(128), 0, stream>>>(W, blob);

    const int n_tokens = 4 * 4096;             // 16384
    router_mfma_kernel<<<dim3(n_tokens / TOKW), dim3(512), 0, stream>>>(X, blob, Bv, out);
}

// Round 13
// 85.048 us; speedup vs baseline: 1.1253x; 1.1253x over previous
//
#include <hip/hip_runtime.h>
#include <hip/hip_bf16.h>
#include <math.h>
#include <stdint.h>

#define DM 4096
#define NEXP 64
#define BK 32              // k per chunk
#define NCH (DM / BK)      // 128 chunks
#define TOKW 64            // tokens per block
#define NSLICE 8           // K-slices (waves: 8 slices x 2 expert-halves)
#define CHPS (NCH / NSLICE)// 16 chunks per slice
#define NTOK 16384

typedef short bf16x8 __attribute__((ext_vector_type(8)));
typedef float f32x4  __attribute__((ext_vector_type(4)));

// RN split: x = hi + lo + f, |f| <= 2^-18 |x|. lo = x - hi is Sterbenz-exact.
__device__ __forceinline__ void split2(float f0, float f1, uint32_t& hw, uint32_t& lw) {
    float2 ff; ff.x = f0; ff.y = f1;
    __hip_bfloat162 h = __float22bfloat162_rn(ff);
    union { __hip_bfloat162 b; uint32_t u; } ch; ch.b = h;
    hw = ch.u;
    float h0 = __bfloat162float(h.x);
    float h1 = __bfloat162float(h.y);
    float2 gg; gg.x = f0 - h0; gg.y = f1 - h1;
    __hip_bfloat162 l = __float22bfloat162_rn(gg);
    union { __hip_bfloat162 b; uint32_t u; } cl; cl.b = l;
    lw = cl.u;
}

// ---------------- pre-pass: W fp32 -> RN bf16 hi/lo, fragment-ordered blob ----------------
// BK=32 layout: byte = c*8192 + n4*1024 + ln*16 (hi; +4096 lo)
// where ln = (e&15) | (kgran<<4), kgran = 0..3 (8 bf16 each), n4 = e>>4.
__global__ __launch_bounds__(256) void wsplit_kernel(const float* __restrict__ W,
                                                     char* __restrict__ blob) {
    const int c   = blockIdx.x;        // 0..127
    const int tid = threadIdx.x;       // 0..255
    const int e   = tid >> 2;          // expert 0..63
    const int g   = tid & 3;           // k-granule 0..3 (8 bf16 each)

    const float* src = W + (size_t)e * DM + c * BK + g * 8;
    float x[8];
    *(float4*)(x)     = *(const float4*)(src);
    *(float4*)(x + 4) = *(const float4*)(src + 4);

    uint32_t hiw[4], low[4];
#pragma unroll
    for (int j = 0; j < 4; ++j) split2(x[2 * j], x[2 * j + 1], hiw[j], low[j]);

    const int ln = (e & 15) | (g << 4);
    const int n4 = e >> 4;
    const size_t base = (size_t)c * 8192 + (size_t)n4 * 1024 + (size_t)ln * 16;
    *(uint4*)(blob + base)        = *(uint4*)hiw;   // hi plane
    *(uint4*)(blob + base + 4096) = *(uint4*)low;   // lo plane
}

// ---------------- main kernel ----------------
// 1024 threads = 16 waves = 8 K-slices x 2 expert-halves; no barriers in the
// K-loop. Wave (eh, ksl): tokens = all 64 of the block (m=4 tiles of 16),
// experts [eh*32,+32) (n=2), chunks [ksl*16,+16) (= same contiguous 512-k
// slice as the 74us r11 kernel -> bit-identical logits). B-L2 traffic halves
// to 256 MB (256 blocks x 1 MiB). 3-product split GEMM: hh + hl + lh.
__global__ __launch_bounds__(1024) void router_mfma_kernel(
    const float* __restrict__ X,
    const char* __restrict__ blob,
    const float* __restrict__ Bv,
    float* __restrict__ out)
{
    __shared__ float part[NSLICE][TOKW][NEXP];   // 128 KiB

    const int tid  = threadIdx.x;      // 0..1023
    const int lane = tid & 63;
    const int wv   = tid >> 6;         // 0..15
    const int eh   = wv & 1;           // expert half
    const int ksl  = wv >> 1;          // K-slice 0..7
    const long tok0 = (long)blockIdx.x * TOKW;

    const int tk = lane & 15;          // token row / expert col within tile
    const int kg = lane >> 4;          // k-granule within 32-k chunk

    // per-lane A row base (floats) for m=0; m-tiles offset by 16*DM
    const float* a0 = X + (size_t)(tok0 + tk) * DM + kg * 8;

    f32x4 acc[4][2];
#pragma unroll
    for (int m = 0; m < 4; ++m)
#pragma unroll
        for (int n = 0; n < 2; ++n) acc[m][n] = (f32x4)0.0f;

    const int c0 = ksl * CHPS;
#pragma unroll 1
    for (int ci = 0; ci < CHPS; ++ci) {
        const int c = c0 + ci;

        // ---- A: 8 floats per m-tile, per-lane direct from global ----
        float ar[4][8];
#pragma unroll
        for (int m = 0; m < 4; ++m) {
            const float* p = a0 + (size_t)m * (16 * DM) + c * BK;
            *(float4*)(ar[m])     = *(const float4*)(p);
            *(float4*)(ar[m] + 4) = *(const float4*)(p + 4);
        }

        // split to fragments (frees ar)
        bf16x8 ah[4], al[4];
#pragma unroll
        for (int m = 0; m < 4; ++m) {
            uint32_t hw[4], lw[4];
#pragma unroll
            for (int j = 0; j < 4; ++j)
                split2(ar[m][2 * j], ar[m][2 * j + 1], hw[j], lw[j]);
            ah[m] = *(bf16x8*)hw;
            al[m] = *(bf16x8*)lw;
        }

        // ---- B from L2 (fragment-ordered blob) + MFMA (3 products) ----
        const char* bb = blob + (size_t)c * 8192;
#pragma unroll
        for (int n = 0; n < 2; ++n) {
            const size_t bo = (size_t)(eh * 2 + n) * 1024 + (size_t)lane * 16;
            bf16x8 bh = *(const bf16x8*)(bb + bo);
            bf16x8 bl = *(const bf16x8*)(bb + 4096 + bo);
#pragma unroll
            for (int m = 0; m < 4; ++m) {
                acc[m][n] = __builtin_amdgcn_mfma_f32_16x16x32_bf16(ah[m], bh, acc[m][n], 0, 0, 0);
                acc[m][n] = __builtin_amdgcn_mfma_f32_16x16x32_bf16(ah[m], bl, acc[m][n], 0, 0, 0);
                acc[m][n] = __builtin_amdgcn_mfma_f32_16x16x32_bf16(al[m], bh, acc[m][n], 0, 0, 0);
            }
        }
    }

    // ---- write per-slice partial logits: token = m*16 + kg*4 + r, expert = eh*32 + n*16 + tk ----
#pragma unroll
    for (int m = 0; m < 4; ++m)
#pragma unroll
        for (int n = 0; n < 2; ++n)
#pragma unroll
            for (int r = 0; r < 4; ++r)
                part[ksl][m * 16 + kg * 4 + r][eh * 32 + n * 16 + tk] = acc[m][n][r];
    __syncthreads();

    // ---- reduce over K-slices: 4096 cells, 4 per thread ----
#pragma unroll
    for (int i = 0; i < 4; ++i) {
        const int cell = tid + i * 1024;
        const int t = cell >> 6;
        const int e = cell & 63;
        float s = part[0][t][e];
#pragma unroll
        for (int w = 1; w < NSLICE; ++w) s += part[w][t][e];
        part[0][t][e] = s;
    }
    __syncthreads();

    // ---- epilogue: bias + softmax + top-2 + dense scatter (lane = expert) ----
    const float bias = Bv[lane];
#pragma unroll 1
    for (int j = 0; j < 4; ++j) {
        const int t = wv * 4 + j;
        float v = part[0][t][lane] + bias;

        float m1 = v;        int i1 = lane;
        float m2 = -3.4e38f; int i2 = 127;
#pragma unroll
        for (int s = 1; s < 64; s <<= 1) {
            float om1 = __shfl_xor(m1, s, 64);
            int   oi1 = __shfl_xor(i1, s, 64);
            float om2 = __shfl_xor(m2, s, 64);
            int   oi2 = __shfl_xor(i2, s, 64);
            bool bw2 = (om1 > m1) || (om1 == m1 && oi1 < i1);
            float l1v = bw2 ? m1 : om1;  int l1i = bw2 ? i1 : oi1;
            float w2v = bw2 ? om2 : m2;  int w2i = bw2 ? oi2 : i2;
            if (bw2) { m1 = om1; i1 = oi1; }
            bool tw = (l1v > w2v) || (l1v == w2v && l1i < w2i);
            m2 = tw ? l1v : w2v;  i2 = tw ? l1i : w2i;
        }

        float p = expf(v - m1);
        float ssum = p;
#pragma unroll
        for (int s = 1; s < 64; s <<= 1) ssum += __shfl_xor(ssum, s, 64);

        float sc = (lane == i1 || lane == i2) ? (p / ssum) : 0.0f;
        out[(size_t)(tok0 + t) * NEXP + lane] = sc;
    }
}

extern "C" void kernel_launch(void* const* d_in, const int* in_sizes, int n_in,
                              void* d_out, int out_size, void* d_ws, size_t ws_size,
                              hipStream_t stream) {
    const float* X  = (const float*)d_in[0];   // [4,4096,4096] fp32
    const float* W  = (const float*)d_in[1];   // [64,4096] fp32
    const float* Bv = (const float*)d_in[2];   // [64] fp32
    float* out = (float*)d_out;                // [4,4096,64] fp32

    // W split blob: 128 chunks * 8 KiB = 1 MiB in d_ws
    char* blob = (char*)d_ws;
    wsplit_kernel<<<dim3(NCH), dim3(256), 0, stream>>>(W, blob);

    router_mfma_kernel<<<dim3(NTOK / TOKW), dim3(1024), 0, stream>>>(X, blob, Bv, out);
}

// Round 14
// 75.091 us; speedup vs baseline: 1.2746x; 1.1326x over previous
//
#include <hip/hip_runtime.h>
#include <hip/hip_bf16.h>
#include <math.h>
#include <stdint.h>

#define DM 4096
#define NEXP 64
#define BK 32              // k per chunk
#define NCH (DM / BK)      // 128 chunks
#define TOKW 32            // tokens per block
#define KSPLIT 8           // waves per block; wave owns a contiguous 512-k slice
#define CHPS (NCH / KSPLIT)// 16 chunks per slice
#define NTOK 16384

typedef short bf16x8 __attribute__((ext_vector_type(8)));
typedef float f32x4  __attribute__((ext_vector_type(4)));

#define WAITVM12() { asm volatile("s_waitcnt vmcnt(12)" ::: "memory"); __builtin_amdgcn_sched_barrier(0); }
#define WAITVM8()  { asm volatile("s_waitcnt vmcnt(8)"  ::: "memory"); __builtin_amdgcn_sched_barrier(0); }

// RN split: x = hi + lo + f, |f| <= 2^-18 |x|. lo = x - hi is Sterbenz-exact.
__device__ __forceinline__ void split2(float f0, float f1, uint32_t& hw, uint32_t& lw) {
    float2 ff; ff.x = f0; ff.y = f1;
    __hip_bfloat162 h = __float22bfloat162_rn(ff);
    union { __hip_bfloat162 b; uint32_t u; } ch; ch.b = h;
    hw = ch.u;
    float h0 = __bfloat162float(h.x);
    float h1 = __bfloat162float(h.y);
    float2 gg; gg.x = f0 - h0; gg.y = f1 - h1;
    __hip_bfloat162 l = __float22bfloat162_rn(gg);
    union { __hip_bfloat162 b; uint32_t u; } cl; cl.b = l;
    lw = cl.u;
}

// ---------------- pre-pass: W fp32 -> RN bf16 hi/lo, fragment-ordered blob ----------------
// BK=32 layout: byte = c*8192 + n4*1024 + ln*16 (hi; +4096 lo)
// where ln = (e&15) | (kgran<<4), kgran = 0..3 (8 bf16 each), n4 = e>>4.
__global__ __launch_bounds__(256) void wsplit_kernel(const float* __restrict__ W,
                                                     char* __restrict__ blob) {
    const int c   = blockIdx.x;        // 0..127
    const int tid = threadIdx.x;       // 0..255
    const int e   = tid >> 2;          // expert 0..63
    const int g   = tid & 3;           // k-granule 0..3 (8 bf16 each)

    const float* src = W + (size_t)e * DM + c * BK + g * 8;
    float x[8];
    *(float4*)(x)     = *(const float4*)(src);
    *(float4*)(x + 4) = *(const float4*)(src + 4);

    uint32_t hiw[4], low[4];
#pragma unroll
    for (int j = 0; j < 4; ++j) split2(x[2 * j], x[2 * j + 1], hiw[j], low[j]);

    const int ln = (e & 15) | (g << 4);
    const int n4 = e >> 4;
    const size_t base = (size_t)c * 8192 + (size_t)n4 * 1024 + (size_t)ln * 16;
    *(uint4*)(blob + base)        = *(uint4*)hiw;   // hi plane
    *(uint4*)(blob + base + 4096) = *(uint4*)low;   // lo plane
}

// ---------------- main kernel ----------------
// 512 thr = 8 waves; wave wv owns chunks [wv*16, +16) (contiguous 512 k) for
// the block's 32 tokens. A (=X) staged to LDS via global_load_lds in exact
// fragment order (per-lane global src, linear LDS dst), D=2 ring per wave,
// counted vmcnt — staging stays in flight across the whole compute phase.
// No barriers in the K-loop. 3-product split GEMM: hh + hl + lh.
__global__ __launch_bounds__(512, 4) void router_mfma_kernel(
    const float* __restrict__ X,
    const char* __restrict__ blob,
    const float* __restrict__ Bv,
    float* __restrict__ out)
{
    __shared__ __align__(16) char smem[65536];   // 8 waves x 2 bufs x 4KB; part overlays after K-loop

    const int tid  = threadIdx.x;      // 0..511
    const int lane = tid & 63;
    const int wv   = tid >> 6;         // 0..7 = K-slice
    const long tok0 = (long)blockIdx.x * TOKW;

    const int tk = lane & 15;          // token row / expert col
    const int kg = lane >> 4;          // k-granule within 32-k chunk

    char* wbase = smem + wv * 8192;
    const int c0 = wv * CHPS;

    // stage chunk c into buf b: 4 x global_load_lds (1KB each), segment (m,h)
    auto stage = [&](int c, int b) {
#pragma unroll
        for (int m = 0; m < 2; ++m)
#pragma unroll
            for (int h = 0; h < 2; ++h) {
                const float* src = X + (size_t)(tok0 + m * 16 + tk) * DM + c * BK + kg * 8 + h * 4;
                char* dst = wbase + b * 4096 + (m * 2 + h) * 1024 + lane * 16;
                __builtin_amdgcn_global_load_lds(
                    (const __attribute__((address_space(1))) void*)src,
                    (__attribute__((address_space(3))) void*)dst, 16, 0, 0);
            }
    };

    f32x4 acc[2][4];
#pragma unroll
    for (int m = 0; m < 2; ++m)
#pragma unroll
        for (int n = 0; n < 4; ++n) acc[m][n] = (f32x4)0.0f;

    // ---- prologue: stage chunks 0,1 ----
    stage(c0 + 0, 0);
    stage(c0 + 1, 1);

#pragma unroll 1
    for (int ci = 0; ci < CHPS; ++ci) {
        const int c = c0 + ci;
        const int b = ci & 1;

        // ---- B loads first (fly during the wait) ----
        const char* bb = blob + (size_t)c * 8192;
        bf16x8 bh[4], bl[4];
#pragma unroll
        for (int n = 0; n < 4; ++n) {
            const size_t bo = (size_t)n * 1024 + (size_t)lane * 16;
            bh[n] = *(const bf16x8*)(bb + bo);
            bl[n] = *(const bf16x8*)(bb + 4096 + bo);
        }

        // ---- wait for buf b (chunk ci) staged; leave B(8) + stage(ci+1)(4) in flight ----
        if (ci < CHPS - 1) { WAITVM12(); } else { WAITVM8(); }

        // ---- fragments from LDS + split ----
        bf16x8 ah[2], al[2];
#pragma unroll
        for (int m = 0; m < 2; ++m) {
            const char* fb = wbase + b * 4096 + m * 2048 + lane * 16;
            f32x4 f0 = *(const f32x4*)(fb);
            f32x4 f1 = *(const f32x4*)(fb + 1024);
            uint32_t hw[4], lw[4];
            split2(f0.x, f0.y, hw[0], lw[0]);
            split2(f0.z, f0.w, hw[1], lw[1]);
            split2(f1.x, f1.y, hw[2], lw[2]);
            split2(f1.z, f1.w, hw[3], lw[3]);
            ah[m] = *(bf16x8*)hw;
            al[m] = *(bf16x8*)lw;
        }

        // ---- stage chunk ci+2 into buf b (its ds_reads are complete) ----
        if (ci + 2 < CHPS) stage(c0 + ci + 2, b);
        __builtin_amdgcn_sched_barrier(0);

        // ---- MFMA (3 products; compiler's B-wait leaves staging in flight) ----
#pragma unroll
        for (int n = 0; n < 4; ++n)
#pragma unroll
            for (int m = 0; m < 2; ++m) {
                acc[m][n] = __builtin_amdgcn_mfma_f32_16x16x32_bf16(ah[m], bh[n], acc[m][n], 0, 0, 0);
                acc[m][n] = __builtin_amdgcn_mfma_f32_16x16x32_bf16(ah[m], bl[n], acc[m][n], 0, 0, 0);
                acc[m][n] = __builtin_amdgcn_mfma_f32_16x16x32_bf16(al[m], bh[n], acc[m][n], 0, 0, 0);
            }
    }

    // ---- partial logits overlay each wave's own (retired) staging region ----
    // part[w][t][e] = float at smem + w*8192 + (t*64+e)*4 ; token = m*16+kg*4+r, expert = n*16+tk
    float* pf = (float*)smem;
#pragma unroll
    for (int m = 0; m < 2; ++m)
#pragma unroll
        for (int n = 0; n < 4; ++n)
#pragma unroll
            for (int r = 0; r < 4; ++r)
                pf[wv * 2048 + (m * 16 + kg * 4 + r) * 64 + n * 16 + tk] = acc[m][n][r];
    __syncthreads();

    // ---- reduce over K-slices: 2048 cells, 4 per thread ----
#pragma unroll
    for (int i = 0; i < 4; ++i) {
        const int cell = tid + i * 512;
        const int t = cell >> 6;
        const int e = cell & 63;
        float s = pf[t * 64 + e];
#pragma unroll
        for (int w = 1; w < KSPLIT; ++w) s += pf[w * 2048 + t * 64 + e];
        pf[t * 64 + e] = s;
    }
    __syncthreads();

    // ---- epilogue: bias + softmax + top-2 + dense scatter (lane = expert) ----
    const float bias = Bv[lane];
#pragma unroll 1
    for (int j = 0; j < TOKW / KSPLIT; ++j) {
        const int t = wv * (TOKW / KSPLIT) + j;
        float v = pf[t * 64 + lane] + bias;

        float m1 = v;        int i1 = lane;
        float m2 = -3.4e38f; int i2 = 127;
#pragma unroll
        for (int s = 1; s < 64; s <<= 1) {
            float om1 = __shfl_xor(m1, s, 64);
            int   oi1 = __shfl_xor(i1, s, 64);
            float om2 = __shfl_xor(m2, s, 64);
            int   oi2 = __shfl_xor(i2, s, 64);
            bool bw2 = (om1 > m1) || (om1 == m1 && oi1 < i1);
            float l1v = bw2 ? m1 : om1;  int l1i = bw2 ? i1 : oi1;
            float w2v = bw2 ? om2 : m2;  int w2i = bw2 ? oi2 : i2;
            if (bw2) { m1 = om1; i1 = oi1; }
            bool tw = (l1v > w2v) || (l1v == w2v && l1i < w2i);
            m2 = tw ? l1v : w2v;  i2 = tw ? l1i : w2i;
        }

        float p = expf(v - m1);
        float ssum = p;
#pragma unroll
        for (int s = 1; s < 64; s <<= 1) ssum += __shfl_xor(ssum, s, 64);

        float sc = (lane == i1 || lane == i2) ? (p / ssum) : 0.0f;
        out[(size_t)(tok0 + t) * NEXP + lane] = sc;
    }
}

extern "C" void kernel_launch(void* const* d_in, const int* in_sizes, int n_in,
                              void* d_out, int out_size, void* d_ws, size_t ws_size,
                              hipStream_t stream) {
    const float* X  = (const float*)d_in[0];   // [4,4096,4096] fp32
    const float* W  = (const float*)d_in[1];   // [64,4096] fp32
    const float* Bv = (const float*)d_in[2];   // [64] fp32
    float* out = (float*)d_out;                // [4,4096,64] fp32

    // W split blob: 128 chunks * 8 KiB = 1 MiB in d_ws
    char* blob = (char*)d_ws;
    wsplit_kernel<<<dim3(NCH), dim3(256), 0, stream>>>(W, blob);

    router_mfma_kernel<<<dim3(NTOK / TOKW), dim3(512), 0, stream>>>(X, blob, Bv, out);
}